// Round 4
// baseline (197.354 us; speedup 1.0000x reference)
//
#include <hip/hip_runtime.h>
#include <math.h>

#define B_ 2
#define DMODEL 128
#define DIN 256
#define DSTATE 16
#define DTR 8
#define OUTC 128
#define Lseq 4096
#define NC 256          // chunks per batch
#define LC 16           // timesteps per chunk

__device__ __forceinline__ float siluf(float x){ return x / (1.f + __expf(-x)); }

// dA[s] = e1^(s+1), s=0..15, via log-depth power ladder (15 muls, depth ~4).
__device__ __forceinline__ void build_dA(float e1, float* dAv){
    float e2 = e1*e1, e4 = e2*e2, e8 = e4*e4;
    dAv[0]=e1;         dAv[1]=e2;         dAv[2]=e2*e1;       dAv[3]=e4;
    dAv[4]=e4*e1;      dAv[5]=e4*e2;      dAv[6]=e4*dAv[2];   dAv[7]=e8;
    dAv[8]=e8*e1;      dAv[9]=e8*e2;      dAv[10]=e8*dAv[2];  dAv[11]=e8*e4;
    dAv[12]=e8*dAv[4]; dAv[13]=e8*dAv[5]; dAv[14]=e8*dAv[6];  dAv[15]=e8*e8;
}

__device__ __forceinline__ float softplusf(float a){
    return (a > 20.f) ? a : __logf(1.f + __expf(a));
}

// ---------------- Kernel AB (fused): in_proj + conv + silu + x_proj + dt_proj + scan pass 1 --------------
// 512 threads/block (4 waves/SIMD at 2 blocks/CU) — round-2 fix for the 20%-occupancy stall.
// Thread t owns output column t of the 512-wide in_proj GEMM (xin cols 0-255 incl. 3-l halo; z cols 256-511).
__global__ __launch_bounds__(512) void k_inconv_scan1(const float* __restrict__ x1,
        const float* __restrict__ Win,
        const float* __restrict__ convw, const float* __restrict__ convb,
        const float* __restrict__ Wx, const float* __restrict__ Wdt,
        const float* __restrict__ bdt, const float* __restrict__ Alog,
        float* __restrict__ zs, float* __restrict__ xc, float* __restrict__ dt,
        float* __restrict__ Bm, float* __restrict__ Cm, float2* __restrict__ PSw){
    __shared__ float xt[128*24];       // x tile [c][p'], p'=0..23 -> l = l0-8+p' (linear float4 copy)
    __shared__ float xcs[16*257];      // conv output [l][d]
    __shared__ float xdbl[16*40];      // x_proj output [l][40]
    int blk = blockIdx.x;              // 512 = b x 256 chunks
    int b  = blk >> 8;
    int cb = blk & 255;
    int l0 = cb << 4;
    int t  = threadIdx.x;

    // ---- phase 0: stage x tile (24 timesteps l0-8..l0+15, zero-fill l<0). addr = 4*e -> linear copy ----
    const float* xb = x1 + (size_t)b * DMODEL * Lseq;
    {
        float4 z4 = make_float4(0.f,0.f,0.f,0.f);
        for (int e = t; e < 128*6; e += 512){
            int c = e / 6, i = e - c*6;
            int l = l0 - 8 + i*4;
            float4 v = (l >= 0) ? *(const float4*)&xb[(size_t)c*Lseq + l] : z4;
            *(float4*)&xt[e*4] = v;    // e*4 == c*24 + i*4
        }
    }
    __syncthreads();

    // ---- phase 1: in_proj GEMM (one Win column per thread) + conv (xin half) / z-gate (z half) ----
    if (t < 256){
        float acc0[19];                // xin[l0-3+p][t], p=0..18
        #pragma unroll
        for (int p=0;p<19;++p) acc0[p]=0.f;
        #pragma unroll 4
        for (int k=0;k<128;++k){
            float w = Win[k*512 + t];
            const float4* xp = (const float4*)&xt[k*24 + 4];   // p' = 4..23 (need 5..23)
            float4 x0=xp[0], x1_=xp[1], x2_=xp[2], x3_=xp[3], x4_=xp[4];
            acc0[0] =fmaf(x0.y, w, acc0[0]);  acc0[1] =fmaf(x0.z, w, acc0[1]);
            acc0[2] =fmaf(x0.w, w, acc0[2]);  acc0[3] =fmaf(x1_.x,w, acc0[3]);
            acc0[4] =fmaf(x1_.y,w, acc0[4]);  acc0[5] =fmaf(x1_.z,w, acc0[5]);
            acc0[6] =fmaf(x1_.w,w, acc0[6]);  acc0[7] =fmaf(x2_.x,w, acc0[7]);
            acc0[8] =fmaf(x2_.y,w, acc0[8]);  acc0[9] =fmaf(x2_.z,w, acc0[9]);
            acc0[10]=fmaf(x2_.w,w, acc0[10]); acc0[11]=fmaf(x3_.x,w, acc0[11]);
            acc0[12]=fmaf(x3_.y,w, acc0[12]); acc0[13]=fmaf(x3_.z,w, acc0[13]);
            acc0[14]=fmaf(x3_.w,w, acc0[14]); acc0[15]=fmaf(x4_.x,w, acc0[15]);
            acc0[16]=fmaf(x4_.y,w, acc0[16]); acc0[17]=fmaf(x4_.z,w, acc0[17]);
            acc0[18]=fmaf(x4_.w,w, acc0[18]);
        }
        // causal depthwise conv + silu straight from registers
        float cw0 = convw[t*4+0], cw1 = convw[t*4+1], cw2 = convw[t*4+2], cw3 = convw[t*4+3];
        float bb = convb[t];
        float* xcg = xc + ((size_t)(b*Lseq + l0))*DIN + t;
        #pragma unroll
        for (int l = 0; l < 16; ++l){
            float acc = bb;
            acc = fmaf(acc0[l],   cw0, acc);
            acc = fmaf(acc0[l+1], cw1, acc);
            acc = fmaf(acc0[l+2], cw2, acc);
            acc = fmaf(acc0[l+3], cw3, acc);
            float v = siluf(acc);
            xcs[l*257 + t] = v;
            xcg[l*DIN] = v;
        }
    } else {
        float acc1[16];                // z[l0+p][t-256], p=0..15
        #pragma unroll
        for (int p=0;p<16;++p) acc1[p]=0.f;
        #pragma unroll 4
        for (int k=0;k<128;++k){
            float w = Win[k*512 + t];
            const float4* yp = (const float4*)&xt[k*24 + 8];   // p' = 8..23 -> l = l0..l0+15
            float4 y0=yp[0], y1=yp[1], y2=yp[2], y3=yp[3];
            acc1[0] =fmaf(y0.x, w, acc1[0]);  acc1[1] =fmaf(y0.y, w, acc1[1]);
            acc1[2] =fmaf(y0.z, w, acc1[2]);  acc1[3] =fmaf(y0.w, w, acc1[3]);
            acc1[4] =fmaf(y1.x, w, acc1[4]);  acc1[5] =fmaf(y1.y, w, acc1[5]);
            acc1[6] =fmaf(y1.z, w, acc1[6]);  acc1[7] =fmaf(y1.w, w, acc1[7]);
            acc1[8] =fmaf(y2.x, w, acc1[8]);  acc1[9] =fmaf(y2.y, w, acc1[9]);
            acc1[10]=fmaf(y2.z, w, acc1[10]); acc1[11]=fmaf(y2.w, w, acc1[11]);
            acc1[12]=fmaf(y3.x, w, acc1[12]); acc1[13]=fmaf(y3.y, w, acc1[13]);
            acc1[14]=fmaf(y3.z, w, acc1[14]); acc1[15]=fmaf(y3.w, w, acc1[15]);
        }
        float* zp = zs + ((size_t)(b*Lseq + l0))*DIN + (t - 256);
        #pragma unroll
        for (int p=0;p<16;++p) zp[p*DIN] = siluf(acc1[p]);
    }
    __syncthreads();

    // ---- phase 3: x_proj (320 threads: 16 rows x 20 col-pairs, float2 weight loads) ----
    if (t < 320){
        int row = t / 20;
        int jg  = t - row*20;
        int j0  = jg * 2;
        float a0=0.f, a1=0.f;
        const float* xrow = xcs + row*257;
        const float* wb = Wx + j0;
        #pragma unroll 8
        for (int d = 0; d < 256; ++d){
            float xv = xrow[d];
            float2 wv = *(const float2*)&wb[d*40];
            a0 = fmaf(xv, wv.x, a0);
            a1 = fmaf(xv, wv.y, a1);
        }
        *(float2*)&xdbl[row*40 + j0] = make_float2(a0, a1);
    }
    __syncthreads();

    // ---- phase 4: dt_proj + softplus + fused scan pass 1 (t<256; t>=256 does B/C extract below) ----
    if (t < 256){
        float wd[DTR];
        #pragma unroll
        for (int r=0;r<DTR;++r) wd[r] = Wdt[r*DIN + t];
        float bv = bdt[t];
        float Av[16];
        {
            const float4* Ap = (const float4*)(Alog + t*DSTATE);
            #pragma unroll
            for (int q=0;q<4;++q){
                float4 a = Ap[q];
                Av[q*4]   = -__expf(a.x);
                Av[q*4+1] = -__expf(a.y);
                Av[q*4+2] = -__expf(a.z);
                Av[q*4+3] = -__expf(a.w);
            }
        }
        bool fastA = true;
        #pragma unroll
        for (int i=1;i<16;++i)
            fastA = fastA && (fabsf(Av[i] - (float)(i+1)*Av[0]) <= 1e-6f*fabsf(Av[i]));
        float P[16], S[16];
        #pragma unroll
        for (int s=0;s<16;++s){ P[s]=1.f; S[s]=0.f; }
        float* dtg = dt + ((size_t)(b*Lseq + l0))*DIN + t;
        #pragma unroll 4
        for (int l=0;l<16;++l){
            float a = bv;
            #pragma unroll
            for (int r=0;r<DTR;++r) a = fmaf(xdbl[l*40 + r], wd[r], a);
            float dtv = softplusf(a);
            dtg[l*DIN] = dtv;
            float xcv = xcs[l*257 + t];
            float dx  = dtv*xcv;
            const float4* Bv = (const float4*)&xdbl[l*40 + DTR];
            float4 B0 = Bv[0], B1 = Bv[1], B2 = Bv[2], B3 = Bv[3];
            float dAv[16];
            if (fastA){
                build_dA(__expf(dtv*Av[0]), dAv);
            } else {
                #pragma unroll
                for (int i=0;i<16;++i) dAv[i] = __expf(dtv*Av[i]);
            }
            #define ST1(i, bval) { P[i] *= dAv[i]; S[i] = fmaf(dAv[i], S[i], dx*(bval)); }
            ST1(0,B0.x) ST1(1,B0.y) ST1(2,B0.z) ST1(3,B0.w)
            ST1(4,B1.x) ST1(5,B1.y) ST1(6,B1.z) ST1(7,B1.w)
            ST1(8,B2.x) ST1(9,B2.y) ST1(10,B2.z) ST1(11,B2.w)
            ST1(12,B3.x) ST1(13,B3.y) ST1(14,B3.z) ST1(15,B3.w)
            #undef ST1
        }
        float2* ps = PSw + ((size_t)(b*NC + cb))*4096 + t*DSTATE;
        #pragma unroll
        for (int s=0;s<16;++s) ps[s] = make_float2(P[s], S[s]);
    }
    // ---- B/C extraction: 512 threads, one element each (xdbl is read-only after phase 3) ----
    {
        int l = t >> 5, q = t & 31;
        float v = xdbl[l*40 + DTR + q];
        size_t g = ((size_t)(b*Lseq + l0 + l))*DSTATE;
        if (q < DSTATE) Bm[g + q] = v;
        else            Cm[g + (q - DSTATE)] = v;
    }
}

// ---------------- Kernel C: pass 2, hierarchical chunk combine ----------------------------------------
__global__ __launch_bounds__(256) void k_scan2(const float2* __restrict__ PSw,
        float* __restrict__ Iw){
    __shared__ float2 gps[16][16];
    __shared__ float  ge [16][16];
    int blk = blockIdx.x;               // 512 = b x 256 channel-groups of 16
    int b  = blk >> 8;
    int r0 = (blk & 255) * 16;
    int t  = threadIdx.x;
    int rr = t & 15;                    // channel within group
    int cg = t >> 4;                    // chunk-group 0..15 (16 chunks each)
    size_t base = ((size_t)(b*NC + cg*16))*4096 + r0 + rr;
    float Pl[16], Sl[16];
    float Pa = 1.f, Sa = 0.f;
    #pragma unroll
    for (int i=0;i<16;++i){
        float2 ps = PSw[base + (size_t)i*4096];
        Pl[i] = ps.x; Sl[i] = ps.y;
        Pa = ps.x * Pa;
        Sa = fmaf(ps.x, Sa, ps.y);
    }
    gps[cg][rr] = make_float2(Pa, Sa);
    __syncthreads();
    if (t < 16){
        float H = 0.f;
        #pragma unroll
        for (int g=0; g<16; ++g){
            float2 ps = gps[g][t];
            ge[g][t] = H;
            H = fmaf(ps.x, H, ps.y);
        }
    }
    __syncthreads();
    float H = ge[cg][rr];
    #pragma unroll
    for (int i=0;i<16;++i){
        Iw[base + (size_t)i*4096] = H;
        H = fmaf(Pl[i], H, Sl[i]);
    }
}

// ---------------- Kernel D: fused scan pass 3 + out_proj + LayerNorm + NCHW store -----------------------
// 512 threads/block: scan on t<256, out_proj 1l x 4c per thread across all 512, LN per-l in half-waves.
__global__ __launch_bounds__(512) void k_scan3out(const float* __restrict__ dt,
        const float* __restrict__ xc, const float* __restrict__ zs,
        const float* __restrict__ Bm, const float* __restrict__ Cm,
        const float* __restrict__ Alog, const float* __restrict__ Dv,
        const float* __restrict__ Iw,
        const float* __restrict__ Wout, const float* __restrict__ lng,
        const float* __restrict__ lnb, float* __restrict__ out){
    __shared__ float ysm[256*18];      // [d][l] stride 18
    __shared__ float os[128*18];       // [c][l] stride 18
    __shared__ float Bs[LC*DSTATE];    // 256
    __shared__ float Cs[LC*DSTATE];
    int blk = blockIdx.x;
    int b = blk >> 8, c = blk & 255;
    int l0 = c * LC;
    int t = threadIdx.x;
    size_t gb = (size_t)(b*Lseq + l0);
    if (t < 256) Bs[t]       = Bm[gb*DSTATE + t];
    else         Cs[t - 256] = Cm[gb*DSTATE + (t - 256)];

    float Av[16], h[16], dtv[LC], xcv[LC], zvv[LC];
    float Dd = 0.f;
    bool fastA = true;
    if (t < 256){
        const float4* Ap = (const float4*)(Alog + t*DSTATE);
        #pragma unroll
        for (int q=0;q<4;++q){
            float4 a = Ap[q];
            Av[q*4]   = -__expf(a.x);
            Av[q*4+1] = -__expf(a.y);
            Av[q*4+2] = -__expf(a.z);
            Av[q*4+3] = -__expf(a.w);
        }
        #pragma unroll
        for (int i=1;i<16;++i)
            fastA = fastA && (fabsf(Av[i] - (float)(i+1)*Av[0]) <= 1e-6f*fabsf(Av[i]));
        const float4* Ip = (const float4*)(Iw + ((size_t)(b*NC + c))*4096 + t*DSTATE);
        #pragma unroll
        for (int q=0;q<4;++q){
            float4 v = Ip[q];
            h[q*4]=v.x; h[q*4+1]=v.y; h[q*4+2]=v.z; h[q*4+3]=v.w;
        }
        Dd = Dv[t];
        const float* dtp = dt + gb*DIN + t;
        const float* xcp = xc + gb*DIN + t;
        const float* zsp = zs + gb*DIN + t;
        #pragma unroll
        for (int l=0;l<LC;++l){
            dtv[l] = dtp[l*DIN];
            xcv[l] = xcp[l*DIN];
            zvv[l] = zsp[l*DIN];
        }
    }
    __syncthreads();
    if (t < 256){
        #pragma unroll
        for (int l=0;l<LC;++l){
            float dtl = dtv[l];
            float dx  = dtl*xcv[l];
            const float4* Bv = (const float4*)&Bs[l*DSTATE];
            const float4* Cv = (const float4*)&Cs[l*DSTATE];
            float4 B0 = Bv[0], B1 = Bv[1], B2 = Bv[2], B3 = Bv[3];
            float4 C0 = Cv[0], C1 = Cv[1], C2 = Cv[2], C3 = Cv[3];
            float dAv[16];
            if (fastA){
                build_dA(__expf(dtl*Av[0]), dAv);
            } else {
                #pragma unroll
                for (int i=0;i<16;++i) dAv[i] = __expf(dtl*Av[i]);
            }
            float y = 0.f;
            #define ST3(i, bval, cval) { h[i] = fmaf(dAv[i], h[i], dx*(bval)); y = fmaf(h[i], (cval), y); }
            ST3(0,B0.x,C0.x) ST3(1,B0.y,C0.y) ST3(2,B0.z,C0.z) ST3(3,B0.w,C0.w)
            ST3(4,B1.x,C1.x) ST3(5,B1.y,C1.y) ST3(6,B1.z,C1.z) ST3(7,B1.w,C1.w)
            ST3(8,B2.x,C2.x) ST3(9,B2.y,C2.y) ST3(10,B2.z,C2.z) ST3(11,B2.w,C2.w)
            ST3(12,B3.x,C3.x) ST3(13,B3.y,C3.y) ST3(14,B3.z,C3.z) ST3(15,B3.w,C3.w)
            #undef ST3
            ysm[t*18 + l] = (y + Dd*xcv[l])*zvv[l];
        }
    }
    __syncthreads();
    // ---- out_proj: 512 threads, 1 l x 4 c each. lg = t>>5 (0..15), cg = t&31 -> c0 = cg*4.
    int lg = t >> 5, cg = t & 31;
    int c0 = cg*4;
    float a0=0.f, a1=0.f, a2=0.f, a3=0.f;
    #pragma unroll 4
    for (int k=0;k<DIN;++k){
        float yv = ysm[k*18 + lg];
        float4 wv = *(const float4*)&Wout[k*OUTC + c0];
        a0 = fmaf(yv, wv.x, a0);
        a1 = fmaf(yv, wv.y, a1);
        a2 = fmaf(yv, wv.z, a2);
        a3 = fmaf(yv, wv.w, a3);
    }
    // LayerNorm over c: reduce across the 32 lanes sharing this l (xor<=16 stays in half-wave)
    {
        float4 gm = *(const float4*)&lng[c0];
        float4 bt = *(const float4*)&lnb[c0];
        float rs = a0+a1+a2+a3;
        #pragma unroll
        for (int m=16;m>0;m>>=1) rs += __shfl_xor(rs, m, 64);
        float mu = rs * (1.f/128.f);
        float d0 = a0-mu, d1 = a1-mu, d2 = a2-mu, d3 = a3-mu;
        float sq = d0*d0+d1*d1+d2*d2+d3*d3;
        #pragma unroll
        for (int m=16;m>0;m>>=1) sq += __shfl_xor(sq, m, 64);
        float rstd = rsqrtf(sq * (1.f/128.f) + 1e-5f);
        os[(c0+0)*18 + lg] = d0*rstd*gm.x + bt.x;
        os[(c0+1)*18 + lg] = d1*rstd*gm.y + bt.y;
        os[(c0+2)*18 + lg] = d2*rstd*gm.z + bt.z;
        os[(c0+3)*18 + lg] = d3*rstd*gm.w + bt.w;
    }
    __syncthreads();
    // store: cc = t>>2 (0..127), q = t&3 -> 4 consecutive l = one float4 per lane
    {
        int cc = t >> 2, q = t & 3;
        const float* ip = &os[cc*18 + q*4];
        float2 v0 = *(const float2*)(ip);
        float2 v1 = *(const float2*)(ip+2);
        float* op = out + ((size_t)(b*OUTC + cc))*Lseq + l0 + q*4;
        *(float4*)op = make_float4(v0.x, v0.y, v1.x, v1.y);
    }
}

extern "C" void kernel_launch(void* const* d_in, const int* in_sizes, int n_in,
                              void* d_out, int out_size, void* d_ws, size_t ws_size,
                              hipStream_t stream) {
    const float* x1    = (const float*)d_in[0];
    const float* Win   = (const float*)d_in[1];
    const float* convw = (const float*)d_in[2];
    const float* convb = (const float*)d_in[3];
    const float* Wx    = (const float*)d_in[4];
    const float* Wdt   = (const float*)d_in[5];
    const float* bdt   = (const float*)d_in[6];
    const float* Alog  = (const float*)d_in[7];
    const float* Dv    = (const float*)d_in[8];
    const float* Wout  = (const float*)d_in[9];
    const float* lng   = (const float*)d_in[10];
    const float* lnb   = (const float*)d_in[11];
    float* out = (float*)d_out;

    float* ws  = (float*)d_ws;
    float* Iw  = ws;                        // 2,097,152 floats (entry states, written by scan2)
    float* zs  = Iw  + 2097152;             // 2,097,152
    float* xc  = zs  + 2097152;             // 2,097,152
    float* dt  = xc  + 2097152;             // 2,097,152
    float* Bm  = dt  + 2097152;             //   131,072
    float* Cm  = Bm  + 131072;              //   131,072
    float2* PSw = (float2*)(Cm + 131072);   // 2,097,152 float2 (~51.4 MB total)

    k_inconv_scan1<<<512, 512, 0, stream>>>(x1, Win, convw, convb, Wx, Wdt, bdt, Alog,
                                            zs, xc, dt, Bm, Cm, PSw);
    k_scan2       <<<512, 256, 0, stream>>>(PSw, Iw);
    k_scan3out    <<<512, 512, 0, stream>>>(dt, xc, zs, Bm, Cm, Alog, Dv, Iw,
                                            Wout, lng, lnb, out);
}